// Round 13
// baseline (139.569 us; speedup 1.0000x reference)
//
#include <hip/hip_runtime.h>
#include <stdint.h>

typedef unsigned short u16t;
typedef __attribute__((ext_vector_type(8))) short bf16x8;
typedef __attribute__((ext_vector_type(4))) float f32x4;
typedef __attribute__((ext_vector_type(16))) float f32x16;

__device__ __forceinline__ float2 up2(uint32_t u) {
    return make_float2(__uint_as_float(u << 16), __uint_as_float(u & 0xFFFF0000u));
}
__device__ __forceinline__ uint32_t pk_bf16(float a, float b) {
    uint32_t r;
    asm("v_cvt_pk_bf16_f32 %0, %1, %2" : "=v"(r) : "v"(a), "v"(b));
    return r;   // lo16 = bf16(a) RNE, hi16 = bf16(b)
}
__device__ __forceinline__ void gload_lds16(const float* g, float* l) {
    __builtin_amdgcn_global_load_lds(
        (const __attribute__((address_space(1))) void*)g,
        (__attribute__((address_space(3))) void*)l, 16, 0, 0);
}

// pinned 16B global load (phase-3 Wt only: issue->wait->use is immediate,
// no cross-phase liveness -> no copy/spill hazard; proven in R11)
#define GLD4(dst, addr, OFF) \
    asm volatile("global_load_dwordx4 %0, %1, off" OFF : "=&v"(dst) : "v"(addr))

// counted vmcnt wait; "memory" stops memory-op reordering, sched_barrier(0)
// stops VALU use-hoisting (rule #18).
#define WAITV(NLIT) do {                                                   \
    asm volatile("s_waitcnt vmcnt(" #NLIT ")" ::: "memory");               \
    __builtin_amdgcn_sched_barrier(0); } while (0)

#define BARRIER_SOFT() do {                                                \
    asm volatile("s_waitcnt lgkmcnt(0)" ::: "memory");                     \
    __builtin_amdgcn_s_barrier();                                          \
    asm volatile("" ::: "memory");                                         \
    __builtin_amdgcn_sched_barrier(0); } while (0)

// issue 8 Wt loads (2 k-groups x 4 o-blocks), offsets k*2048 + j*512
#define WT_ISSUE8(B, A) do {                                               \
    GLD4(B[0], A, "");                GLD4(B[1], A, " offset:512");        \
    GLD4(B[2], A, " offset:1024");    GLD4(B[3], A, " offset:1536");       \
    GLD4(B[4], A, " offset:2048");    GLD4(B[5], A, " offset:2560");       \
    GLD4(B[6], A, " offset:3072");    GLD4(B[7], A, " offset:3584"); } while (0)

#define P3_PROC2(K, BUF) do {                                              \
    _Pragma("unroll")                                                      \
    for (int kk = 0; kk < 2; ++kk) {                                       \
        const float2* yp = (const float2*)&ys[(g << 6) + (((K) + kk) << 3)];\
        float2 y0 = yp[0], y1 = yp[1], y2 = yp[2], y3 = yp[3];             \
        _Pragma("unroll")                                                  \
        for (int j = 0; j < 4; ++j) {                                      \
            uint4 wq = BUF[kk * 4 + j];                                    \
            ac2[j] += up2(wq.x) * y0;                                      \
            ac2[j] += up2(wq.y) * y1;                                      \
            ac2[j] += up2(wq.z) * y2;                                      \
            ac2[j] += up2(wq.w) * y3;                                      \
        }                                                                  \
    } } while (0)

// issue 12 gload_lds for one tile's f32 data -> xfs (linear, NO dest VGPRs)
#define STAGE_LDS(SRC) do {                                                \
    _Pragma("unroll")                                                      \
    for (int k_ = 0; k_ < 12; ++k_) {                                      \
        const int cb_ = (wid * 12 + k_) << 6;       /* 16B-chunk base */   \
        gload_lds16((SRC) + (size_t)((cb_ + lane) << 2), &xfs[cb_ << 2]);  \
    } } while (0)

// LDS->LDS convert: xfs (f32 linear) -> xbs (bf16, chunk^=(row&7) swizzle)
#define CONVERT() do {                                                     \
    _Pragma("unroll")                                                      \
    for (int k_ = 0; k_ < 12; ++k_) {                                      \
        const int q_ = t + (k_ << 8);               /* 16B chunk 0..3071 */\
        const int row_ = q_ / 96, cc_ = q_ - row_ * 96;                    \
        float4 v_ = *(const float4*)&xfs[q_ << 2];                         \
        uint2 pk_;                                                         \
        pk_.x = pk_bf16(v_.x, v_.y);  pk_.y = pk_bf16(v_.z, v_.w);         \
        const int c8_ = cc_ >> 1, hf_ = cc_ & 1;                           \
        *(uint2*)&xbs[row_ * 384 + (((c8_ ^ (row_ & 7)) << 3) | (hf_ << 2))] = pk_; \
    } } while (0)

// ---------------------------------------------------------------------------
// Pre-kernel (35 blocks):
//  blocks 0-31 : W1d (1024x64 fp32) -> Wt bf16 [g][k][o][j]   (131072 B)
//  blocks 32-34: W2d (16x384 fp32)  -> W2b bf16 [16][384] row-major (12288 B)
// ---------------------------------------------------------------------------
__global__ void __launch_bounds__(256) prep_weights(const float* __restrict__ W1d,
                                                    const float* __restrict__ W2d,
                                                    u16t* __restrict__ Wt,
                                                    uint4* __restrict__ W2b) {
    int bid = blockIdx.x;
    if (bid < 32) {
        int t = bid * 256 + threadIdx.x;          // 0..8191
        int g = t >> 10, k = (t >> 7) & 7, o = t & 127;
        const float* src = W1d + (((g << 7) + o) << 6) + (k << 3);
        u16t* dst = Wt + ((((g << 3) + k) << 7) + o) * 8;
#pragma unroll
        for (int j = 0; j < 8; ++j) {
            uint32_t u = __float_as_uint(src[j]);
            uint32_t r = (u + 0x7FFFu + ((u >> 16) & 1u)) >> 16;   // RN to bf16
            dst[j] = (u16t)r;
        }
    } else {
        int idx = (bid - 32) * 256 + threadIdx.x;  // 0..767 (chunks of 8 f32)
        const float4* s = (const float4*)W2d + idx * 2;
        float4 A = s[0], B = s[1];
        uint4 p;
        p.x = pk_bf16(A.x, A.y); p.y = pk_bf16(A.z, A.w);
        p.z = pk_bf16(B.x, B.y); p.w = pk_bf16(B.z, B.w);
        W2b[idx] = p;
    }
}

#define NT 8   // tiles per persistent block; grid = 4096/NT = 512 (2 blk/CU)

// ---------------------------------------------------------------------------
// Persistent pipelined kernel.  Per tile:
//   phase2 MFMA conv2d (xbs) -> lgkm -> phase3 Wt-asm conv1d + softmax ->
//   STAGE_LDS(next tile -> xfs, in flight) -> zs barrier -> phase4 MFMA
//   mixing + 48 plain stores -> WAITV(48) (48 stores younger; my 12 gload_lds
//   are oldest -> complete; extra compiler loads are older -> drained too) ->
//   barrier -> CONVERT (xfs -> xbs) -> barrier.
// No asm-output register lives across a phase: gload_lds has no registers.
// LDS: 49152 + 24576 + 2048 + 2560 = 78336 B -> exactly 2 blocks/CU.
// ---------------------------------------------------------------------------
template <bool WBF>
__global__ void __launch_bounds__(256, 2) dynamixer_fused(
    const float* __restrict__ x,
    const float* __restrict__ W2d,
    const float* __restrict__ b2d,
    const float* __restrict__ W1d,
    const float* __restrict__ b1d,
    const u16t* __restrict__ Wt,
    const u16t* __restrict__ W2b,
    float* __restrict__ out)
{
    __shared__ alignas(16) float xfs[32 * 384];   // f32 stage (linear)
    __shared__ alignas(16) u16t xbs[32 * 384];    // bf16 tile (swizzled)
    __shared__ alignas(16) float ys[512];         // y, flat e*32+w
    __shared__ alignas(16) u16t zs16[32 * 40];    // attn bf16, stride 40

    const int t = threadIdx.x;
    const int wid = t >> 6, lane = t & 63;
    const int g2 = lane >> 5, l31 = lane & 31;
    const int g = t >> 5, l = t & 31;
    const int T0 = blockIdx.x * NT;

    // ---------------- prologue: stage + convert tile 0 ----------------
    STAGE_LDS(x + (size_t)T0 * 12288);
    WAITV(0);
    __builtin_amdgcn_s_barrier();
    asm volatile("" ::: "memory");
    CONVERT();
    BARRIER_SOFT();

    for (int it = 0; it < NT; ++it) {
        const size_t base = (size_t)(T0 + it) * 12288;

        // ---------------- phase 2: conv2d via MFMA 16x16x32 ----------------
        {
            const int g4 = lane >> 4, m = lane & 15, f = m & 7;
            f32x4 c0, c1;
#pragma unroll
            for (int r = 0; r < 4; ++r) { c0[r] = 0.f; c1[r] = 0.f; }
            __builtin_amdgcn_s_setprio(1);
#pragma unroll 4
            for (int ks = 0; ks < 12; ++ks) {
                const int ch = ks * 4 + g4;            // logical 16B chunk
                const int d0 = ks * 32 + g4 * 8;
                bf16x8 a;
                if (WBF) {
                    a = *(const bf16x8*)&W2b[m * 384 + d0];
                } else {
                    const float* wf = W2d + m * 384 + d0;
                    float4 wa = *(const float4*)wf, wb = *(const float4*)(wf + 4);
                    union { uint4 u; bf16x8 v; } cvt;
                    cvt.u.x = pk_bf16(wa.x, wa.y); cvt.u.y = pk_bf16(wa.z, wa.w);
                    cvt.u.z = pk_bf16(wb.x, wb.y); cvt.u.w = pk_bf16(wb.z, wb.w);
                    a = cvt.v;
                }
                bf16x8 b0 = *(const bf16x8*)&xbs[m * 384 + ((ch ^ f) << 3)];
                bf16x8 b1 = *(const bf16x8*)&xbs[(m + 16) * 384 + ((ch ^ f) << 3)];
                c0 = __builtin_amdgcn_mfma_f32_16x16x32_bf16(a, b0, c0, 0, 0, 0);
                c1 = __builtin_amdgcn_mfma_f32_16x16x32_bf16(a, b1, c1, 0, 0, 0);
            }
            __builtin_amdgcn_s_setprio(0);
            // write only this wave's e-slice [4*wid, 4*wid+4)
            if (g4 == wid) {
                float4 bb = *(const float4*)&b2d[wid * 4];
                float bbv[4] = {bb.x, bb.y, bb.z, bb.w};
#pragma unroll
                for (int r = 0; r < 4; ++r) {
                    ys[(4 * wid + r) * 32 + m]      = c0[r] + bbv[r];
                    ys[(4 * wid + r) * 32 + 16 + m] = c1[r] + bbv[r];
                }
            }
        }
        asm volatile("s_waitcnt lgkmcnt(0)" ::: "memory");   // ys intra-wave
        __builtin_amdgcn_sched_barrier(0);

        // ---------------- phase 3: conv1d (asm dbuf Wt) + softmax ----------
        {
            float2 ac2[4];
#pragma unroll
            for (int j = 0; j < 4; ++j) ac2[j] = make_float2(0.f, 0.f);
            if (WBF) {
                uint4 bufA[8], bufB[8];
                uint64_t wa = (uint64_t)(uintptr_t)Wt + ((uint32_t)g << 14)
                            + ((uint32_t)l << 4);
                WT_ISSUE8(bufA, wa);  wa += 4096;      // k = 0,1
                WT_ISSUE8(bufB, wa);  wa += 4096;      // k = 2,3
                WAITV(8);
                P3_PROC2(0, bufA);
                WT_ISSUE8(bufA, wa);  wa += 4096;      // k = 4,5
                WAITV(8);
                P3_PROC2(2, bufB);
                WT_ISSUE8(bufB, wa);                    // k = 6,7
                WAITV(8);
                P3_PROC2(4, bufA);
                WAITV(0);
                P3_PROC2(6, bufB);
            } else {
#pragma unroll
                for (int k = 0; k < 8; ++k) {
                    const float2* yp = (const float2*)&ys[(g << 6) + (k << 3)];
                    float2 y0 = yp[0], y1 = yp[1], y2 = yp[2], y3 = yp[3];
#pragma unroll
                    for (int j = 0; j < 4; ++j) {
                        const float2* wr = (const float2*)(W1d + (((g << 7) + l + (j << 5)) << 6) + (k << 3));
                        ac2[j] += wr[0] * y0;
                        ac2[j] += wr[1] * y1;
                        ac2[j] += wr[2] * y2;
                        ac2[j] += wr[3] * y3;
                    }
                }
            }
            float acc[4];
#pragma unroll
            for (int j = 0; j < 4; ++j)
                acc[j] = ac2[j].x + ac2[j].y + b1d[(g << 7) + (j << 5) + l];

            // softmax over v (= lane within 32-lane group), row u = 4g+j
#pragma unroll
            for (int j = 0; j < 4; ++j) {
                float mx = acc[j];
#pragma unroll
                for (int s = 16; s >= 1; s >>= 1) mx = fmaxf(mx, __shfl_xor(mx, s, 32));
                float p = __expf(acc[j] - mx);
                float ssum = p;
#pragma unroll
                for (int s = 16; s >= 1; s >>= 1) ssum += __shfl_xor(ssum, s, 32);
                float pv = __fdividef(p, ssum);
                zs16[((g << 2) + j) * 40 + l] = (u16t)pk_bf16(pv, pv);
            }
        }

        // ---------------- issue next tile's staging (no registers) --------
        if (it < NT - 1) {
            STAGE_LDS(x + base + 12288);
        }

        // zs barrier — gload_lds stay in flight across it
        BARRIER_SOFT();

        // ---------------- phase 4: out = attn . x via MFMA 32x32x16 -------
        {
            bf16x8 A0 = *(const bf16x8*)&zs16[l31 * 40 + g2 * 8];
            bf16x8 A1 = *(const bf16x8*)&zs16[l31 * 40 + 16 + g2 * 8];
            float* __restrict__ obase = out + base;
#pragma unroll
            for (int ii = 0; ii < 3; ++ii) {
                const int d = wid * 96 + ii * 32 + l31;
                const int ch = d >> 3, off = d & 7;
                bf16x8 B0, B1;
#pragma unroll
                for (int j = 0; j < 8; ++j) {
                    B0[j] = (short)xbs[(g2 * 8 + j) * 384 + ((ch ^ j) << 3) + off];
                    B1[j] = (short)xbs[(16 + g2 * 8 + j) * 384 + ((ch ^ j) << 3) + off];
                }
                f32x16 acc16;
#pragma unroll
                for (int r = 0; r < 16; ++r) acc16[r] = 0.f;
                __builtin_amdgcn_s_setprio(1);
                acc16 = __builtin_amdgcn_mfma_f32_32x32x16_bf16(A0, B0, acc16, 0, 0, 0);
                acc16 = __builtin_amdgcn_mfma_f32_32x32x16_bf16(A1, B1, acc16, 0, 0, 0);
                __builtin_amdgcn_s_setprio(0);
#pragma unroll
                for (int r = 0; r < 16; ++r) {
                    const int u = (r & 3) + 8 * (r >> 2) + 4 * g2;
                    obase[u * 384 + d] = acc16[r];
                }
            }
        }

        // ---------------- finish stage: convert f32 -> bf16 tile ----------
        if (it < NT - 1) {
            WAITV(48);   // 48 stores younger; my 12 gload_lds (oldest) done
            __builtin_amdgcn_s_barrier();
            asm volatile("" ::: "memory");
            CONVERT();
            BARRIER_SOFT();
        }
    }
}

// ---------------------------------------------------------------------------
extern "C" void kernel_launch(void* const* d_in, const int* in_sizes, int n_in,
                              void* d_out, int out_size, void* d_ws, size_t ws_size,
                              hipStream_t stream) {
    const float* x   = (const float*)d_in[0];
    const float* W2d = (const float*)d_in[1];
    const float* b2d = (const float*)d_in[2];
    const float* W1d = (const float*)d_in[3];
    const float* b1d = (const float*)d_in[4];
    float* out = (float*)d_out;

    const size_t wt_bytes  = 8 * 8 * 128 * 8 * sizeof(u16t);   // 131072
    const size_t w2b_bytes = 16 * 384 * sizeof(u16t);          // 12288
    if (ws_size >= wt_bytes + w2b_bytes) {
        u16t* Wt = (u16t*)d_ws;
        u16t* W2b = (u16t*)((char*)d_ws + wt_bytes);
        prep_weights<<<35, 256, 0, stream>>>(W1d, W2d, Wt, (uint4*)W2b);
        dynamixer_fused<true><<<4096 / NT, 256, 0, stream>>>(x, W2d, b2d, W1d, b1d, Wt, W2b, out);
    } else {
        dynamixer_fused<false><<<4096 / NT, 256, 0, stream>>>(x, W2d, b2d, W1d, b1d, nullptr, nullptr, out);
    }
}